// Round 4
// baseline (511.727 us; speedup 1.0000x reference)
//
#include <hip/hip_runtime.h>

typedef __bf16 bf16x8 __attribute__((ext_vector_type(8)));
typedef float  f32x4  __attribute__((ext_vector_type(4)));
typedef unsigned int u32x4 __attribute__((ext_vector_type(4)));

#define MFMA(a, b, c) __builtin_amdgcn_mfma_f32_16x16x32_bf16((a), (b), (c), 0, 0, 0)

#define THREADS 1024
#define WAVES   16
#define CPW     4     // crystals per wave
#define CPB     64    // crystals per block (16 waves x 4)
#define MT      32    // nodes per tile (2 x 16-row halves)

// workspace layout: [seg table][bf16 weight pack]
#define SEG_INTS  16416
#define SEG_BYTES (SEG_INTS * 4)       // 65664
#define O_WM1 0
#define O_WM2 65536
#define O_WA1 131072
#define O_WA2 262144
#define W_ELEMS 262656
#define W_BYTES (W_ELEMS * 2)          // 525312

// LDS weight region byte offsets (within wlds): three 128-row x 256 B panels
#define LA1B 0        // Wa1 node half (cols 0..127)
#define LM1B 32768    // Wm1
#define LM2B 65536    // Wm2   (end 98304)

__device__ __forceinline__ bf16x8 cvt8(const float* pf) {
    float4 a = *(const float4*)pf, b = *(const float4*)(pf + 4);
    bf16x8 o;
    o[0] = (__bf16)a.x; o[1] = (__bf16)a.y; o[2] = (__bf16)a.z; o[3] = (__bf16)a.w;
    o[4] = (__bf16)b.x; o[5] = (__bf16)b.y; o[6] = (__bf16)b.z; o[7] = (__bf16)b.w;
    return o;
}

__device__ __forceinline__ unsigned pk2(float a, float b) {
    unsigned short ua = __builtin_bit_cast(unsigned short, (__bf16)a);
    unsigned short ub = __builtin_bit_cast(unsigned short, (__bf16)b);
    return (unsigned)ua | ((unsigned)ub << 16);
}

__device__ __forceinline__ int lower_bound(const int* __restrict__ a, int n, int v) {
    int lo = 0, hi = n;
    while (lo < hi) { int mid = (lo + hi) >> 1; if (a[mid] < v) lo = mid + 1; else hi = mid; }
    return lo;
}

// ---------------------------------------------------------------------------
// Merged prep: blocks [0, segBlocks) build seg[c] = lower_bound(index, c);
// blocks [segBlocks, ...) pack the 4 f32 weight tensors into contiguous bf16.
// ---------------------------------------------------------------------------
__global__ __launch_bounds__(256) void prep2_kernel(
    const float* __restrict__ Wm1, const float* __restrict__ Wm2,
    const float* __restrict__ Wa1, const float* __restrict__ Wa2,
    const int* __restrict__ index, int N, int S, int segBlocks,
    int* __restrict__ seg, __bf16* __restrict__ wb, int doPack)
{
    const int b = blockIdx.x;
    if (b < segBlocks) {
        int c = b * 256 + threadIdx.x;
        if (c <= S) seg[c] = lower_bound(index, N, c);
    } else if (doPack) {
        int i8 = (b - segBlocks) * 256 + threadIdx.x;
        if (i8 >= W_ELEMS / 8) return;
        int i = i8 * 8;
        const float* src; int s;
        if      (i < O_WM2) { src = Wm1; s = i; }
        else if (i < O_WA1) { src = Wm2; s = i - O_WM2; }
        else if (i < O_WA2) { src = Wa1; s = i - O_WA1; }
        else                { src = Wa2; s = i - O_WA2; }
        *(bf16x8*)(wb + i) = cvt8(src + s);
    }
}

// ---------------------------------------------------------------------------
// Fused kernel, weight-stationary, 16 waves/block (4 waves/SIMD).
// Block = one head x 64 crystals; wave w owns crystals [c0+4w, c0+4w+4):
// no main-loop barriers. Head's Wa1-node-half/Wm1/Wm2 staged once in LDS
// (96 KiB, XOR-swizzled); Wa1 cry-half read from global only in the
// once-per-wave cry precompute. Per 32-node tile, two 16-row halves are
// processed fully (GEMM3->logits, GEMM1 swapped + repack, GEMM2, softmax
// walk) to keep peak live registers ~<=128 (no scratch spills).
// MFMA 16x16x32 bf16: A/B[idx=lane&15][k=(lane>>4)*8+j]; D col=lane&15,
// row=(lane>>4)*4+reg.
// ---------------------------------------------------------------------------
template<bool WB, bool SEG>
__global__ __launch_bounds__(THREADS, 4) void fused5_kernel(
    const float* __restrict__ fea, const float* __restrict__ cry,
    const float* __restrict__ Wm1, const float* __restrict__ bm1,
    const float* __restrict__ Wm2, const float* __restrict__ bm2,
    const float* __restrict__ Wa1, const float* __restrict__ ba1,
    const float* __restrict__ Wa2, const float* __restrict__ ba2,
    const __bf16* __restrict__ wb, const int* __restrict__ seg,
    const int* __restrict__ index, int N, int S, float* __restrict__ out)
{
    __shared__ __align__(16) __bf16 wlds[49152];       // 96 KiB weights
    __shared__ float crylds[WAVES][CPW][128];           // 32 KiB cry.Wa1cry^T
    __shared__ float bm1lds[128];                       // 512 B

    const int h  = blockIdx.x & 3;
    const int c0 = (blockIdx.x >> 2) * CPB;
    const int t  = threadIdx.x;
    const int lane = t & 63, w = t >> 6, ml = lane & 15, q = lane >> 4;
    const int swzb = (ml & 7) << 4;
    const char* wbytes = (const char*)wlds;

    // ---- stage weights (swizzled source -> linear LDS); 3 panels of 32 KiB --
#pragma unroll
    for (int i = 0; i < 6; i++) {
        const int cb = (t + i * THREADS) << 4;   // [0, 98304)
        const int r = cb >> 15;
        const int local = cb & 32767;
        const int row = local >> 8;
        const int col8 = ((((local >> 4) & 15) ^ (row & 7)) << 3);
        bf16x8 v;
        if (r == 0) {
            if constexpr (WB) v = *(const bf16x8*)(wb + O_WA1 + (size_t)h * 32768 + row * 256 + col8);
            else              v = cvt8(Wa1 + (size_t)h * 32768 + (size_t)row * 256 + col8);
        } else if (r == 1) {
            if constexpr (WB) v = *(const bf16x8*)(wb + O_WM1 + (size_t)h * 16384 + row * 128 + col8);
            else              v = cvt8(Wm1 + (size_t)h * 16384 + (size_t)row * 128 + col8);
        } else {
            if constexpr (WB) v = *(const bf16x8*)(wb + O_WM2 + (size_t)h * 16384 + row * 128 + col8);
            else              v = cvt8(Wm2 + (size_t)h * 16384 + (size_t)row * 128 + col8);
        }
        *(bf16x8*)((char*)wlds + cb) = v;
    }
    if (t < 32) *(float4*)&bm1lds[t * 4] = *(const float4*)&bm1[h * 128 + t * 4];
    __syncthreads();

    // ---- per-wave crystal range ----
    const int cw0 = min(c0 + w * CPW, S);
    const int cw1 = min(cw0 + CPW, S);
    int start, end;
    if constexpr (SEG) { start = seg[cw0]; end = seg[cw1]; }
    else { start = lower_bound(index, N, cw0); end = lower_bound(index, N, cw1); }

    // ---- hoisted per-lane biases (col = ot*16+ml of head h) ----
    float ba1v[8], bb2[8], wa2v[8];
#pragma unroll
    for (int ot = 0; ot < 8; ot++) {
        ba1v[ot] = ba1[h * 128 + ot * 16 + ml];
        bb2[ot]  = bm2[h * 128 + ot * 16 + ml];
        wa2v[ot] = Wa2[h * 128 + ot * 16 + ml];
    }
    const float ba2v = ba2[h];

    // ---- precompute cry contribution: D[crystal r][o] = cry_c . Wa1cry^T ----
    // (Wa1 cry-half fragments read from global; once per wave)
    {
        bf16x8 cf[4];
#pragma unroll
        for (int kk = 0; kk < 4; kk++) {
            bf16x8 z;
#pragma unroll
            for (int j = 0; j < 8; j++) z[j] = (__bf16)0.f;
            if (ml < CPW && cw0 + ml < S)
                z = cvt8(cry + (size_t)(cw0 + ml) * 128 + kk * 32 + q * 8);
            cf[kk] = z;
        }
#pragma unroll
        for (int ot = 0; ot < 8; ot++) {
            f32x4 acc = {0.f, 0.f, 0.f, 0.f};
#pragma unroll
            for (int kk = 0; kk < 4; kk++) {
                bf16x8 B;
                size_t off = (size_t)h * 32768 + (size_t)(ot * 16 + ml) * 256 + 128 + kk * 32 + q * 8;
                if constexpr (WB) B = *(const bf16x8*)(wb + O_WA1 + off);
                else              B = cvt8(Wa1 + off);
                acc = MFMA(cf[kk], B, acc);
            }
            if (q == 0) {
#pragma unroll
                for (int r = 0; r < 4; r++) crylds[w][r][ot * 16 + ml] = acc[r];
            }
        }
    }

    float m_run = -1e30f, d_run = 0.f;
    float wacc[8] = {0.f,0.f,0.f,0.f,0.f,0.f,0.f,0.f};
    int cur_c = -1, emit_c = cw0;

    auto flushf = [&]() {
        float inv = 1.f / (d_run + 1e-16f);
        for (int z = emit_c; z < cur_c; z++)   // zero-fill empty crystals
            *(float2*)&out[(size_t)z * 512 + h * 128 + lane * 2] = make_float2(0.f, 0.f);
#pragma unroll
        for (int ot = 0; ot < 8; ot++) {
            float v = wacc[ot];
            v += __shfl_xor(v, 16);
            v += __shfl_xor(v, 32);
            if (q == 0) out[(size_t)cur_c * 512 + h * 128 + ot * 16 + ml] = v * inv;
            wacc[ot] = 0.f;
        }
        emit_c = cur_c + 1;
        m_run = -1e30f; d_run = 0.f;
    };

    for (int tb = start; tb < end; tb += MT) {
        int nv = end - tb; if (nv > MT) nv = MT;

        // ---- per-lane node index (rows 0..31 on lanes 0..31) ----
        const int iv = (lane < nv) ? index[tb + lane] : cw0;

        // ---- run-boundary mask for the whole tile ----
        unsigned long long bmask;
        {
            int ivp = __shfl(iv, lane > 0 ? lane - 1 : 0);
            bmask = __ballot(lane < nv && (lane == 0 || iv != ivp));
        }

        // ---- two 16-row halves, fully processed in sequence ----
        for (int s = 0; s < 2; s++) {
            const int lo = s * 16;
            if (lo >= nv) break;
            int hcnt = nv - lo; if (hcnt > 16) hcnt = 16;

            // -- fea fragments for this half (f32 -> bf16, zero-pad) --
            bf16x8 afh[4];
            {
                const int row = lo + ml;
                const bool val = row < nv;
#pragma unroll
                for (int kk = 0; kk < 4; kk++) {
                    bf16x8 z;
#pragma unroll
                    for (int j = 0; j < 8; j++) z[j] = (__bf16)0.f;
                    if (val) z = cvt8(fea + (size_t)(tb + row) * 128 + kk * 32 + q * 8);
                    afh[kk] = z;
                }
            }

            // -- GEMM3 (node half of Wa1; cry half as acc-init) -> logits --
            float lv4[4];
            {
                int cl4[4];
#pragma unroll
                for (int r = 0; r < 4; r++)
                    cl4[r] = __shfl(iv, lo + q * 4 + r) - cw0;
                float lsum[4] = {0.f, 0.f, 0.f, 0.f};
#pragma unroll
                for (int ot = 0; ot < 8; ot++) {
                    bf16x8 B[4];
#pragma unroll
                    for (int kk = 0; kk < 4; kk++)
                        B[kk] = *(const bf16x8*)(wbytes + LA1B + (ot * 16 + ml) * 256 + ((((kk * 4 + q) << 4)) ^ swzb));
                    const int oc = ot * 16 + ml;
                    f32x4 acc;
#pragma unroll
                    for (int r = 0; r < 4; r++) acc[r] = crylds[w][cl4[r]][oc];
#pragma unroll
                    for (int kk = 0; kk < 4; kk++) acc = MFMA(afh[kk], B[kk], acc);
#pragma unroll
                    for (int r = 0; r < 4; r++) {
                        float v = acc[r] + ba1v[ot]; v = v >= 0.f ? v : 0.01f * v;
                        lsum[r] += v * wa2v[ot];
                    }
                }
#pragma unroll
                for (int rr = 0; rr < 4; rr++) {
                    float x = lsum[rr];
                    x += __shfl_xor(x, 1); x += __shfl_xor(x, 2);
                    x += __shfl_xor(x, 4); x += __shfl_xor(x, 8);
                    lv4[rr] = x + ba2v;   // logit of row lo + q*4 + rr
                }
            }

            // -- GEMM1 swapped (A=Wm1, B=fea half) + in-register repack --
            bf16x8 a2h[4];
#pragma unroll
            for (int kk = 0; kk < 4; kk++) {
                unsigned pw[2][2];   // [otl][p]
#pragma unroll
                for (int otl = 0; otl < 2; otl++) {
                    const int ot = kk * 2 + otl;
                    bf16x8 A[4];
#pragma unroll
                    for (int k4 = 0; k4 < 4; k4++)
                        A[k4] = *(const bf16x8*)(wbytes + LM1B + (ot * 16 + ml) * 256 + ((((k4 * 4 + q) << 4)) ^ swzb));
                    const float4 bq = *(const float4*)&bm1lds[ot * 16 + q * 4];
                    f32x4 acc = {0.f, 0.f, 0.f, 0.f};
#pragma unroll
                    for (int k4 = 0; k4 < 4; k4++) acc = MFMA(A[k4], afh[k4], acc);
                    float v0 = acc[0] + bq.x, v1 = acc[1] + bq.y;
                    float v2 = acc[2] + bq.z, v3 = acc[3] + bq.w;
                    v0 = v0 >= 0.f ? v0 : 0.01f * v0;  v1 = v1 >= 0.f ? v1 : 0.01f * v1;
                    v2 = v2 >= 0.f ? v2 : 0.01f * v2;  v3 = v3 >= 0.f ? v3 : 0.01f * v3;
                    pw[otl][0] = pk2(v0, v1);
                    pw[otl][1] = pk2(v2, v3);
                }
                const int srcLo = (((2 * q) & 3) << 4) + ml;
                const int srcHi = (((2 * q + 1) & 3) << 4) + ml;
                const bool hiSel = (q >> 1) & 1;
                unsigned l0a = (unsigned)__shfl((int)pw[0][0], srcLo);
                unsigned l0b = (unsigned)__shfl((int)pw[1][0], srcLo);
                unsigned l1a = (unsigned)__shfl((int)pw[0][1], srcLo);
                unsigned l1b = (unsigned)__shfl((int)pw[1][1], srcLo);
                unsigned h0a = (unsigned)__shfl((int)pw[0][0], srcHi);
                unsigned h0b = (unsigned)__shfl((int)pw[1][0], srcHi);
                unsigned h1a = (unsigned)__shfl((int)pw[0][1], srcHi);
                unsigned h1b = (unsigned)__shfl((int)pw[1][1], srcHi);
                u32x4 wv4u = { hiSel ? l0b : l0a, hiSel ? l1b : l1a,
                               hiSel ? h0b : h0a, hiSel ? h1b : h1a };
                a2h[kk] = __builtin_bit_cast(bf16x8, wv4u);
            }

            // -- GEMM2 (bias-initialized accumulators) --
            f32x4 acc2h[8];
#pragma unroll
            for (int ot = 0; ot < 8; ot++) {
                bf16x8 B[4];
#pragma unroll
                for (int kk = 0; kk < 4; kk++)
                    B[kk] = *(const bf16x8*)(wbytes + LM2B + (ot * 16 + ml) * 256 + ((((kk * 4 + q) << 4)) ^ swzb));
                f32x4 acc = {bb2[ot], bb2[ot], bb2[ot], bb2[ot]};
#pragma unroll
                for (int kk = 0; kk < 4; kk++) acc = MFMA(a2h[kk], B[kk], acc);
                acc2h[ot] = acc;
            }

            // -- run walk for this half's rows [lo, lo+hcnt) --
            unsigned hm = (unsigned)((bmask >> lo) & 0xffffull) | 1u;
            if (hcnt < 16) hm &= (1u << hcnt) - 1u;
            while (hm) {
                int a = (int)__builtin_ctz(hm);
                hm &= hm - 1u;
                int b = hm ? (int)__builtin_ctz(hm) : hcnt;
                int c = __shfl(iv, lo + a);
                if (c != cur_c) {
                    if (cur_c >= 0) flushf();
                    cur_c = c;
                }
                float tmax = -1e30f;
#pragma unroll
                for (int rr = 0; rr < 4; rr++) {
                    int row = q * 4 + rr;
                    if (row >= a && row < b) tmax = fmaxf(tmax, lv4[rr]);
                }
                tmax = fmaxf(tmax, __shfl_xor(tmax, 16));
                tmax = fmaxf(tmax, __shfl_xor(tmax, 32));
                float m_new = fmaxf(m_run, tmax);
                float scf = __expf(m_run - m_new);
                d_run *= scf;
#pragma unroll
                for (int ot = 0; ot < 8; ot++) wacc[ot] *= scf;
                m_run = m_new;

                float wv4[4]; float dp = 0.f;
#pragma unroll
                for (int rr = 0; rr < 4; rr++) {
                    int row = q * 4 + rr;
                    float ww = (row >= a && row < b) ? __expf(lv4[rr] - m_run) : 0.f;
                    wv4[rr] = ww; dp += ww;
                }
                dp += __shfl_xor(dp, 16);
                dp += __shfl_xor(dp, 32);
                d_run += dp;
#pragma unroll
                for (int ot = 0; ot < 8; ot++) {
                    f32x4 acc = acc2h[ot];
                    wacc[ot] += wv4[0] * acc[0] + wv4[1] * acc[1]
                              + wv4[2] * acc[2] + wv4[3] * acc[3];
                }
            }
        }
    }

    if (cur_c >= 0) flushf();
    for (int z = emit_c; z < cw1; z++)   // trailing empty crystals
        *(float2*)&out[(size_t)z * 512 + h * 128 + lane * 2] = make_float2(0.f, 0.f);
}

// ---------------------------------------------------------------------------
extern "C" void kernel_launch(void* const* d_in, const int* in_sizes, int n_in,
                              void* d_out, int out_size, void* d_ws, size_t ws_size,
                              hipStream_t stream)
{
    const float* fea = (const float*)d_in[0];
    const float* cry = (const float*)d_in[1];
    const float* Wm1 = (const float*)d_in[2];
    const float* bm1 = (const float*)d_in[3];
    const float* Wm2 = (const float*)d_in[4];
    const float* bm2 = (const float*)d_in[5];
    const float* Wa1 = (const float*)d_in[6];
    const float* ba1 = (const float*)d_in[7];
    const float* Wa2 = (const float*)d_in[8];
    const float* ba2 = (const float*)d_in[9];
    const int* index = (const int*)d_in[10];

    const int N = in_sizes[0] / 128;      // 200000
    const int S = out_size / 512;         // 16384
    const int grid = 4 * ((S + CPB - 1) / CPB);

    const int segBlocks  = (S + 1 + 255) / 256;
    const int packBlocks = (W_ELEMS / 8 + 255) / 256;
    const bool segFits = (S + 1) <= SEG_INTS;
    const size_t needSeg  = (size_t)SEG_BYTES;
    const size_t needFull = (size_t)SEG_BYTES + (size_t)W_BYTES;

    if (segFits && ws_size >= needFull) {
        int* seg = (int*)d_ws;
        __bf16* wbp = (__bf16*)((char*)d_ws + SEG_BYTES);
        prep2_kernel<<<segBlocks + packBlocks, 256, 0, stream>>>(
            Wm1, Wm2, Wa1, Wa2, index, N, S, segBlocks, seg, wbp, 1);
        fused5_kernel<true, true><<<grid, THREADS, 0, stream>>>(
            fea, cry, Wm1, bm1, Wm2, bm2, Wa1, ba1, Wa2, ba2,
            wbp, seg, index, N, S, (float*)d_out);
    } else if (segFits && ws_size >= needSeg) {
        int* seg = (int*)d_ws;
        prep2_kernel<<<segBlocks, 256, 0, stream>>>(
            Wm1, Wm2, Wa1, Wa2, index, N, S, segBlocks, seg, nullptr, 0);
        fused5_kernel<false, true><<<grid, THREADS, 0, stream>>>(
            fea, cry, Wm1, bm1, Wm2, bm2, Wa1, ba1, Wa2, ba2,
            nullptr, seg, index, N, S, (float*)d_out);
    } else {
        fused5_kernel<false, false><<<grid, THREADS, 0, stream>>>(
            fea, cry, Wm1, bm1, Wm2, bm2, Wa1, ba1, Wa2, ba2,
            nullptr, nullptr, index, N, S, (float*)d_out);
    }
}

// Round 5
// 461.098 us; speedup vs baseline: 1.1098x; 1.1098x over previous
//
#include <hip/hip_runtime.h>

typedef __bf16 bf16x8 __attribute__((ext_vector_type(8)));
typedef float  f32x4  __attribute__((ext_vector_type(4)));
typedef unsigned int u32x4 __attribute__((ext_vector_type(4)));

#define MFMA(a, b, c) __builtin_amdgcn_mfma_f32_16x16x32_bf16((a), (b), (c), 0, 0, 0)

#define THREADS 1024
#define WAVES   16
#define CPW     4     // crystals per wave
#define CPB     64    // crystals per block (16 waves x 4)
#define MT      32    // nodes per tile (2 x 16-row halves)

// workspace layout: [seg table][bf16 weight pack][bf16 cry][bf16 fea]
#define SEG_INTS  16416
#define SEG_BYTES (SEG_INTS * 4)       // 65664
#define O_WM1 0
#define O_WM2 65536
#define O_WA1 131072
#define O_WA2 262144
#define W_ELEMS 262656
#define W_BYTES (W_ELEMS * 2)          // 525312

// LDS weight region byte offsets (within wlds): three 128-row x 256 B panels
#define LA1B 0        // Wa1 node half (cols 0..127)
#define LM1B 32768    // Wm1
#define LM2B 65536    // Wm2   (end 98304)

__device__ __forceinline__ bf16x8 cvt8(const float* pf) {
    float4 a = *(const float4*)pf, b = *(const float4*)(pf + 4);
    bf16x8 o;
    o[0] = (__bf16)a.x; o[1] = (__bf16)a.y; o[2] = (__bf16)a.z; o[3] = (__bf16)a.w;
    o[4] = (__bf16)b.x; o[5] = (__bf16)b.y; o[6] = (__bf16)b.z; o[7] = (__bf16)b.w;
    return o;
}

__device__ __forceinline__ unsigned pk2(float a, float b) {
    unsigned short ua = __builtin_bit_cast(unsigned short, (__bf16)a);
    unsigned short ub = __builtin_bit_cast(unsigned short, (__bf16)b);
    return (unsigned)ua | ((unsigned)ub << 16);
}

__device__ __forceinline__ int lower_bound(const int* __restrict__ a, int n, int v) {
    int lo = 0, hi = n;
    while (lo < hi) { int mid = (lo + hi) >> 1; if (a[mid] < v) lo = mid + 1; else hi = mid; }
    return lo;
}

// ---------------------------------------------------------------------------
// Merged prep: block ranges do [seg table][weight pack][cry cast][fea cast].
// bf16 casts are bitwise-identical to the in-kernel cvt8 rounding.
// ---------------------------------------------------------------------------
__global__ __launch_bounds__(256) void prep3_kernel(
    const float* __restrict__ Wm1, const float* __restrict__ Wm2,
    const float* __restrict__ Wa1, const float* __restrict__ Wa2,
    const float* __restrict__ fea, const float* __restrict__ cry,
    const int* __restrict__ index, int N, int S,
    int segBlocks, int packBlocks, int cryBlocks,
    int* __restrict__ seg, __bf16* __restrict__ wb,
    __bf16* __restrict__ cryb, __bf16* __restrict__ feab, int full)
{
    int b = blockIdx.x;
    if (b < segBlocks) {
        int c = b * 256 + threadIdx.x;
        if (c <= S) seg[c] = lower_bound(index, N, c);
        return;
    }
    if (!full) return;
    b -= segBlocks;
    if (b < packBlocks) {
        int i8 = b * 256 + threadIdx.x;
        if (i8 >= W_ELEMS / 8) return;
        int i = i8 * 8;
        const float* src; int s;
        if      (i < O_WM2) { src = Wm1; s = i; }
        else if (i < O_WA1) { src = Wm2; s = i - O_WM2; }
        else if (i < O_WA2) { src = Wa1; s = i - O_WA1; }
        else                { src = Wa2; s = i - O_WA2; }
        *(bf16x8*)(wb + i) = cvt8(src + s);
        return;
    }
    b -= packBlocks;
    if (b < cryBlocks) {
        int i = b * 256 + threadIdx.x;
        if (i < S * 16) *(bf16x8*)(cryb + (size_t)i * 8) = cvt8(cry + (size_t)i * 8);
        return;
    }
    b -= cryBlocks;
    int i = b * 256 + threadIdx.x;
    if (i < N * 16) *(bf16x8*)(feab + (size_t)i * 8) = cvt8(fea + (size_t)i * 8);
}

// ---------------------------------------------------------------------------
// Fused kernel, weight-stationary, 16 waves/block (4 waves/SIMD, 1 block/CU).
// Block = one head x 64 crystals; wave w owns crystals [c0+4w, c0+4w+4):
// no main-loop barriers. XCD-aware mapping: the 4 head-blocks sharing a
// crystal group land on the SAME XCD (same b%8), so fea is fetched once per
// XCD L2 instead of 4x. Head's Wa1-node-half/Wm1/Wm2 staged once in LDS
// (96 KiB, XOR-swizzled); Wa1 cry-half used only in the once-per-wave cry
// precompute. Per 32-node tile, two 16-row halves are processed fully
// (GEMM3->logits, GEMM1 swapped + repack, GEMM2, softmax walk) to keep peak
// live registers ~100 (no scratch spills; no launch_bounds 2nd arg -- the
// compiler's 16-wave launchability constraint caps VGPR at 128).
// MFMA 16x16x32 bf16: A/B[idx=lane&15][k=(lane>>4)*8+j]; D col=lane&15,
// row=(lane>>4)*4+reg.
// ---------------------------------------------------------------------------
template<bool WB, bool SEG, bool FB>
__global__ __launch_bounds__(THREADS) void fused6_kernel(
    const float* __restrict__ fea, const float* __restrict__ cry,
    const float* __restrict__ Wm1, const float* __restrict__ bm1,
    const float* __restrict__ Wm2, const float* __restrict__ bm2,
    const float* __restrict__ Wa1, const float* __restrict__ ba1,
    const float* __restrict__ Wa2, const float* __restrict__ ba2,
    const __bf16* __restrict__ wb, const int* __restrict__ seg,
    const __bf16* __restrict__ feab, const __bf16* __restrict__ cryb,
    const int* __restrict__ index, int N, int S, float* __restrict__ out)
{
    __shared__ __align__(16) __bf16 wlds[49152];       // 96 KiB weights
    __shared__ float crylds[WAVES][CPW][128];           // 32 KiB cry.Wa1cry^T
    __shared__ float bm1lds[128];                       // 512 B

    // ---- XCD-aware block -> (head, crystal-group) mapping ----
    const int G = (S + CPB - 1) / CPB;
    int h, cg;
    if ((G & 7) == 0) {
        const int xcd = blockIdx.x & 7, j = blockIdx.x >> 3;
        h = j & 3; cg = xcd + 8 * (j >> 2);
    } else {
        h = blockIdx.x & 3; cg = blockIdx.x >> 2;
    }
    const int c0 = cg * CPB;
    const int t  = threadIdx.x;
    const int lane = t & 63, w = t >> 6, ml = lane & 15, q = lane >> 4;
    const int swzb = (ml & 7) << 4;
    const char* wbytes = (const char*)wlds;

    // ---- stage weights (swizzled source -> linear LDS); 3 panels of 32 KiB --
#pragma unroll
    for (int i = 0; i < 6; i++) {
        const int cb = (t + i * THREADS) << 4;   // [0, 98304)
        const int r = cb >> 15;
        const int local = cb & 32767;
        const int row = local >> 8;
        const int col8 = ((((local >> 4) & 15) ^ (row & 7)) << 3);
        bf16x8 v;
        if (r == 0) {
            if constexpr (WB) v = *(const bf16x8*)(wb + O_WA1 + (size_t)h * 32768 + row * 256 + col8);
            else              v = cvt8(Wa1 + (size_t)h * 32768 + (size_t)row * 256 + col8);
        } else if (r == 1) {
            if constexpr (WB) v = *(const bf16x8*)(wb + O_WM1 + (size_t)h * 16384 + row * 128 + col8);
            else              v = cvt8(Wm1 + (size_t)h * 16384 + (size_t)row * 128 + col8);
        } else {
            if constexpr (WB) v = *(const bf16x8*)(wb + O_WM2 + (size_t)h * 16384 + row * 128 + col8);
            else              v = cvt8(Wm2 + (size_t)h * 16384 + (size_t)row * 128 + col8);
        }
        *(bf16x8*)((char*)wlds + cb) = v;
    }
    if (t < 32) *(float4*)&bm1lds[t * 4] = *(const float4*)&bm1[h * 128 + t * 4];
    __syncthreads();

    // ---- per-wave crystal range ----
    const int cw0 = min(c0 + w * CPW, S);
    const int cw1 = min(cw0 + CPW, S);
    int start, end;
    if constexpr (SEG) { start = seg[cw0]; end = seg[cw1]; }
    else { start = lower_bound(index, N, cw0); end = lower_bound(index, N, cw1); }

    // ---- hoisted per-lane biases (col = ot*16+ml of head h) ----
    float ba1v[8], bb2[8], wa2v[8];
#pragma unroll
    for (int ot = 0; ot < 8; ot++) {
        ba1v[ot] = ba1[h * 128 + ot * 16 + ml];
        bb2[ot]  = bm2[h * 128 + ot * 16 + ml];
        wa2v[ot] = Wa2[h * 128 + ot * 16 + ml];
    }
    const float ba2v = ba2[h];

    // ---- precompute cry contribution: D[crystal r][o] = cry_c . Wa1cry^T ----
    {
        bf16x8 cf[4];
#pragma unroll
        for (int kk = 0; kk < 4; kk++) {
            bf16x8 z;
#pragma unroll
            for (int j = 0; j < 8; j++) z[j] = (__bf16)0.f;
            if (ml < CPW && cw0 + ml < S) {
                if constexpr (FB) z = *(const bf16x8*)(cryb + (size_t)(cw0 + ml) * 128 + kk * 32 + q * 8);
                else              z = cvt8(cry + (size_t)(cw0 + ml) * 128 + kk * 32 + q * 8);
            }
            cf[kk] = z;
        }
#pragma unroll
        for (int ot = 0; ot < 8; ot++) {
            f32x4 acc = {0.f, 0.f, 0.f, 0.f};
#pragma unroll
            for (int kk = 0; kk < 4; kk++) {
                bf16x8 B;
                size_t off = (size_t)h * 32768 + (size_t)(ot * 16 + ml) * 256 + 128 + kk * 32 + q * 8;
                if constexpr (WB) B = *(const bf16x8*)(wb + O_WA1 + off);
                else              B = cvt8(Wa1 + off);
                acc = MFMA(cf[kk], B, acc);
            }
            if (q == 0) {
#pragma unroll
                for (int r = 0; r < 4; r++) crylds[w][r][ot * 16 + ml] = acc[r];
            }
        }
    }

    float m_run = -1e30f, d_run = 0.f;
    float wacc[8] = {0.f,0.f,0.f,0.f,0.f,0.f,0.f,0.f};
    int cur_c = -1, emit_c = cw0;

    auto flushf = [&]() {
        float inv = 1.f / (d_run + 1e-16f);
        for (int z = emit_c; z < cur_c; z++)   // zero-fill empty crystals
            *(float2*)&out[(size_t)z * 512 + h * 128 + lane * 2] = make_float2(0.f, 0.f);
#pragma unroll
        for (int ot = 0; ot < 8; ot++) {
            float v = wacc[ot];
            v += __shfl_xor(v, 16);
            v += __shfl_xor(v, 32);
            if (q == 0) out[(size_t)cur_c * 512 + h * 128 + ot * 16 + ml] = v * inv;
            wacc[ot] = 0.f;
        }
        emit_c = cur_c + 1;
        m_run = -1e30f; d_run = 0.f;
    };

    for (int tb = start; tb < end; tb += MT) {
        int nv = end - tb; if (nv > MT) nv = MT;

        // ---- per-lane node index (rows 0..31 on lanes 0..31) ----
        const int iv = (lane < nv) ? index[tb + lane] : cw0;

        // ---- run-boundary mask for the whole tile ----
        unsigned long long bmask;
        {
            int ivp = __shfl(iv, lane > 0 ? lane - 1 : 0);
            bmask = __ballot(lane < nv && (lane == 0 || iv != ivp));
        }

        // ---- two 16-row halves, fully processed in sequence ----
        for (int s = 0; s < 2; s++) {
            const int lo = s * 16;
            if (lo >= nv) break;
            int hcnt = nv - lo; if (hcnt > 16) hcnt = 16;

            // -- fea fragments for this half (zero-pad invalid rows) --
            bf16x8 afh[4];
            {
                const int row = lo + ml;
                const bool val = row < nv;
#pragma unroll
                for (int kk = 0; kk < 4; kk++) {
                    bf16x8 z;
#pragma unroll
                    for (int j = 0; j < 8; j++) z[j] = (__bf16)0.f;
                    if (val) {
                        if constexpr (FB) z = *(const bf16x8*)(feab + (size_t)(tb + row) * 128 + kk * 32 + q * 8);
                        else              z = cvt8(fea + (size_t)(tb + row) * 128 + kk * 32 + q * 8);
                    }
                    afh[kk] = z;
                }
            }

            // -- GEMM3 (node half of Wa1; cry half as acc-init) -> logits --
            float lv4[4];
            {
                int cl4[4];
#pragma unroll
                for (int r = 0; r < 4; r++)
                    cl4[r] = __shfl(iv, lo + q * 4 + r) - cw0;
                float lsum[4] = {0.f, 0.f, 0.f, 0.f};
#pragma unroll
                for (int ot = 0; ot < 8; ot++) {
                    bf16x8 B[4];
#pragma unroll
                    for (int kk = 0; kk < 4; kk++)
                        B[kk] = *(const bf16x8*)(wbytes + LA1B + (ot * 16 + ml) * 256 + ((((kk * 4 + q) << 4)) ^ swzb));
                    const int oc = ot * 16 + ml;
                    f32x4 acc;
#pragma unroll
                    for (int r = 0; r < 4; r++) acc[r] = crylds[w][cl4[r]][oc];
#pragma unroll
                    for (int kk = 0; kk < 4; kk++) acc = MFMA(afh[kk], B[kk], acc);
#pragma unroll
                    for (int r = 0; r < 4; r++) {
                        float v = acc[r] + ba1v[ot]; v = v >= 0.f ? v : 0.01f * v;
                        lsum[r] += v * wa2v[ot];
                    }
                }
#pragma unroll
                for (int rr = 0; rr < 4; rr++) {
                    float x = lsum[rr];
                    x += __shfl_xor(x, 1); x += __shfl_xor(x, 2);
                    x += __shfl_xor(x, 4); x += __shfl_xor(x, 8);
                    lv4[rr] = x + ba2v;   // logit of row lo + q*4 + rr
                }
            }

            // -- GEMM1 swapped (A=Wm1, B=fea half) + in-register repack --
            bf16x8 a2h[4];
#pragma unroll
            for (int kk = 0; kk < 4; kk++) {
                unsigned pw[2][2];   // [otl][p]
#pragma unroll
                for (int otl = 0; otl < 2; otl++) {
                    const int ot = kk * 2 + otl;
                    bf16x8 A[4];
#pragma unroll
                    for (int k4 = 0; k4 < 4; k4++)
                        A[k4] = *(const bf16x8*)(wbytes + LM1B + (ot * 16 + ml) * 256 + ((((k4 * 4 + q) << 4)) ^ swzb));
                    const float4 bq = *(const float4*)&bm1lds[ot * 16 + q * 4];
                    f32x4 acc = {0.f, 0.f, 0.f, 0.f};
#pragma unroll
                    for (int k4 = 0; k4 < 4; k4++) acc = MFMA(A[k4], afh[k4], acc);
                    float v0 = acc[0] + bq.x, v1 = acc[1] + bq.y;
                    float v2 = acc[2] + bq.z, v3 = acc[3] + bq.w;
                    v0 = v0 >= 0.f ? v0 : 0.01f * v0;  v1 = v1 >= 0.f ? v1 : 0.01f * v1;
                    v2 = v2 >= 0.f ? v2 : 0.01f * v2;  v3 = v3 >= 0.f ? v3 : 0.01f * v3;
                    pw[otl][0] = pk2(v0, v1);
                    pw[otl][1] = pk2(v2, v3);
                }
                const int srcLo = (((2 * q) & 3) << 4) + ml;
                const int srcHi = (((2 * q + 1) & 3) << 4) + ml;
                const bool hiSel = (q >> 1) & 1;
                unsigned l0a = (unsigned)__shfl((int)pw[0][0], srcLo);
                unsigned l0b = (unsigned)__shfl((int)pw[1][0], srcLo);
                unsigned l1a = (unsigned)__shfl((int)pw[0][1], srcLo);
                unsigned l1b = (unsigned)__shfl((int)pw[1][1], srcLo);
                unsigned h0a = (unsigned)__shfl((int)pw[0][0], srcHi);
                unsigned h0b = (unsigned)__shfl((int)pw[1][0], srcHi);
                unsigned h1a = (unsigned)__shfl((int)pw[0][1], srcHi);
                unsigned h1b = (unsigned)__shfl((int)pw[1][1], srcHi);
                u32x4 wv4u = { hiSel ? l0b : l0a, hiSel ? l1b : l1a,
                               hiSel ? h0b : h0a, hiSel ? h1b : h1a };
                a2h[kk] = __builtin_bit_cast(bf16x8, wv4u);
            }

            // -- GEMM2 (bias-initialized accumulators) --
            f32x4 acc2h[8];
#pragma unroll
            for (int ot = 0; ot < 8; ot++) {
                bf16x8 B[4];
#pragma unroll
                for (int kk = 0; kk < 4; kk++)
                    B[kk] = *(const bf16x8*)(wbytes + LM2B + (ot * 16 + ml) * 256 + ((((kk * 4 + q) << 4)) ^ swzb));
                f32x4 acc = {bb2[ot], bb2[ot], bb2[ot], bb2[ot]};
#pragma unroll
                for (int kk = 0; kk < 4; kk++) acc = MFMA(a2h[kk], B[kk], acc);
                acc2h[ot] = acc;
            }

            // -- run walk for this half's rows [lo, lo+hcnt) --
            unsigned hm = (unsigned)((bmask >> lo) & 0xffffull) | 1u;
            if (hcnt < 16) hm &= (1u << hcnt) - 1u;
            while (hm) {
                int a = (int)__builtin_ctz(hm);
                hm &= hm - 1u;
                int b = hm ? (int)__builtin_ctz(hm) : hcnt;
                int c = __shfl(iv, lo + a);
                if (c != cur_c) {
                    if (cur_c >= 0) flushf();
                    cur_c = c;
                }
                float tmax = -1e30f;
#pragma unroll
                for (int rr = 0; rr < 4; rr++) {
                    int row = q * 4 + rr;
                    if (row >= a && row < b) tmax = fmaxf(tmax, lv4[rr]);
                }
                tmax = fmaxf(tmax, __shfl_xor(tmax, 16));
                tmax = fmaxf(tmax, __shfl_xor(tmax, 32));
                float m_new = fmaxf(m_run, tmax);
                float scf = __expf(m_run - m_new);
                d_run *= scf;
#pragma unroll
                for (int ot = 0; ot < 8; ot++) wacc[ot] *= scf;
                m_run = m_new;

                float wv4[4]; float dp = 0.f;
#pragma unroll
                for (int rr = 0; rr < 4; rr++) {
                    int row = q * 4 + rr;
                    float ww = (row >= a && row < b) ? __expf(lv4[rr] - m_run) : 0.f;
                    wv4[rr] = ww; dp += ww;
                }
                dp += __shfl_xor(dp, 16);
                dp += __shfl_xor(dp, 32);
                d_run += dp;
#pragma unroll
                for (int ot = 0; ot < 8; ot++) {
                    f32x4 acc = acc2h[ot];
                    wacc[ot] += wv4[0] * acc[0] + wv4[1] * acc[1]
                              + wv4[2] * acc[2] + wv4[3] * acc[3];
                }
            }
        }
    }

    if (cur_c >= 0) flushf();
    for (int z = emit_c; z < cw1; z++)   // trailing empty crystals
        *(float2*)&out[(size_t)z * 512 + h * 128 + lane * 2] = make_float2(0.f, 0.f);
}

// ---------------------------------------------------------------------------
extern "C" void kernel_launch(void* const* d_in, const int* in_sizes, int n_in,
                              void* d_out, int out_size, void* d_ws, size_t ws_size,
                              hipStream_t stream)
{
    const float* fea = (const float*)d_in[0];
    const float* cry = (const float*)d_in[1];
    const float* Wm1 = (const float*)d_in[2];
    const float* bm1 = (const float*)d_in[3];
    const float* Wm2 = (const float*)d_in[4];
    const float* bm2 = (const float*)d_in[5];
    const float* Wa1 = (const float*)d_in[6];
    const float* ba1 = (const float*)d_in[7];
    const float* Wa2 = (const float*)d_in[8];
    const float* ba2 = (const float*)d_in[9];
    const int* index = (const int*)d_in[10];

    const int N = in_sizes[0] / 128;      // 200000
    const int S = out_size / 512;         // 16384
    const int G = (S + CPB - 1) / CPB;
    const int grid = 4 * G;

    const int segBlocks  = (S + 1 + 255) / 256;
    const int packBlocks = (W_ELEMS / 8 + 255) / 256;
    const int cryBlocks  = (S * 16 + 255) / 256;
    const int feaBlocks  = (N * 16 + 255) / 256;
    const bool segFits = (S + 1) <= SEG_INTS;

    const size_t wOff   = (size_t)SEG_BYTES;
    const size_t cryOff = wOff + (size_t)W_BYTES;
    const size_t feaOff = cryOff + (size_t)S * 256;
    const size_t needSeg  = (size_t)SEG_BYTES;
    const size_t needFull = feaOff + (size_t)N * 256;

    if (segFits && ws_size >= needFull) {
        int* seg = (int*)d_ws;
        __bf16* wbp  = (__bf16*)((char*)d_ws + wOff);
        __bf16* cryb = (__bf16*)((char*)d_ws + cryOff);
        __bf16* feab = (__bf16*)((char*)d_ws + feaOff);
        prep3_kernel<<<segBlocks + packBlocks + cryBlocks + feaBlocks, 256, 0, stream>>>(
            Wm1, Wm2, Wa1, Wa2, fea, cry, index, N, S,
            segBlocks, packBlocks, cryBlocks, seg, wbp, cryb, feab, 1);
        fused6_kernel<true, true, true><<<grid, THREADS, 0, stream>>>(
            fea, cry, Wm1, bm1, Wm2, bm2, Wa1, ba1, Wa2, ba2,
            wbp, seg, feab, cryb, index, N, S, (float*)d_out);
    } else if (segFits && ws_size >= needSeg) {
        int* seg = (int*)d_ws;
        prep3_kernel<<<segBlocks, 256, 0, stream>>>(
            Wm1, Wm2, Wa1, Wa2, fea, cry, index, N, S,
            segBlocks, packBlocks, cryBlocks, seg, nullptr, nullptr, nullptr, 0);
        fused6_kernel<false, true, false><<<grid, THREADS, 0, stream>>>(
            fea, cry, Wm1, bm1, Wm2, bm2, Wa1, ba1, Wa2, ba2,
            nullptr, seg, nullptr, nullptr, index, N, S, (float*)d_out);
    } else {
        fused6_kernel<false, false, false><<<grid, THREADS, 0, stream>>>(
            fea, cry, Wm1, bm1, Wm2, bm2, Wa1, ba1, Wa2, ba2,
            nullptr, nullptr, nullptr, nullptr, index, N, S, (float*)d_out);
    }
}